// Round 3
// baseline (1055.450 us; speedup 1.0000x reference)
//
#include <hip/hip_runtime.h>

// out[m,n] = sum_k f16(x[m,k]) * W[n,k],  W = codebook[indices].reshape(4096,4096)
// M=8192, N=4096, K=4096, codebook 256x8.
//
// Fully fused single kernel, ZERO workspace use. Each block:
//   1) sniffs input dtypes deterministically (cb: f16-raw / bf16 / f32;
//      x: f32 / bf16; idx: i32 / i64) -- wave-uniform branches,
//   2) decodes the 256x8 codebook into 4 KiB LDS as f16,
//   3) 128x128-tile GEMM, BK=64: A staged via VGPR loads+convert+ds_write,
//      B staged by idx-gather LDS->LDS from the decoded codebook,
//      mfma_f32_16x16x32_f16 core, XOR chunk swizzle on LDS slots,
//   4) epilogue writes f32 (or bf16 if x was bf16).

typedef _Float16 f16;
typedef _Float16 f16x8 __attribute__((ext_vector_type(8)));
typedef float f32x4 __attribute__((ext_vector_type(4)));

#define KDIM 4096
#define NDIM 4096
#define MDIM 8192

__device__ inline float bf16_to_f32(unsigned short w) {
    union { unsigned u; float f; } c; c.u = ((unsigned)w) << 16; return c.f;
}
__device__ inline unsigned short f32_to_bf16(float f) {
    union { float f; unsigned u; } c; c.f = f;
    unsigned r = c.u + 0x7FFFu + ((c.u >> 16) & 1u);   // RNE
    return (unsigned short)(r >> 16);
}

__global__ __launch_bounds__(256) void crom_fused(const void* __restrict__ xraw,
                                                  const void* __restrict__ cbraw,
                                                  const void* __restrict__ idxraw,
                                                  void* __restrict__ outraw) {
    __shared__ __align__(16) f16 cbL[256 * 8];       // decoded codebook, 4 KiB
    __shared__ __align__(16) f16 As[128 * 64];       // 16 KiB
    __shared__ __align__(16) f16 Bs[128 * 64];       // 16 KiB
    __shared__ int flagsL[4];

    const int t = threadIdx.x;

    // ---------------- dtype sniff (deterministic, every block) ----------------
    {
        int c_cb = 0, c_f32ok = 1, c_x = 0, c_z = 0;
        const unsigned short* cbw = (const unsigned short*)cbraw;
        for (int j = 0; j < 8; ++j) {
            int e5 = (cbw[t * 8 + j] >> 10) & 31;     // f16 exponent field
            c_cb += (e5 == 15) || (e5 == 16);         // f16 ~32%, bf16-bits ~99%
        }
        // f32 test on exactly the first 4 KiB (1024 floats): f16 round-trip exact
        const float* cbf = (const float*)cbraw;
        for (int j = 0; j < 4; ++j) {
            float v = cbf[t * 4 + j];
            if (!(__builtin_fabsf(v) < 1024.0f)) c_f32ok = 0;
            else { f16 h = (f16)v; if ((float)h != v) c_f32ok = 0; }
        }
        const unsigned short* xw = (const unsigned short*)xraw;
        for (int j = 0; j < 8; ++j) {
            int e8 = (xw[t * 8 + j] >> 7) & 255;      // bf16 exponent field
            c_x += (e8 >= 115) && (e8 <= 131);        // bf16 ~100%, f32-halves ~53%
        }
        const unsigned* iw = (const unsigned*)idxraw;
        for (int j = 1; j < 8; j += 2) c_z += (iw[t * 8 + j] == 0);  // i64 high words
        if (t < 4) flagsL[t] = 0;
        __syncthreads();
        atomicAdd(&flagsL[0], c_cb);
        atomicAdd(&flagsL[1], c_f32ok);
        atomicAdd(&flagsL[2], c_x);
        atomicAdd(&flagsL[3], c_z);
        __syncthreads();
    }
    const int cb_mode = (flagsL[1] == 256) ? 2 : ((flagsL[0] > 1300) ? 1 : 0); // 0=f16,1=bf16,2=f32
    const int x_bf16  = flagsL[2] > 1600;
    const int idx64   = flagsL[3] > 512;

    // ---------------- decode codebook -> cbL (2048 f16) ------------------------
    if (cb_mode == 2) {
        const float* cf = (const float*)cbraw;        // 8 KiB buffer
        f16x8 h;
        for (int j = 0; j < 8; ++j) h[j] = (f16)cf[t * 8 + j];
        *(f16x8*)&cbL[t * 8] = h;
    } else if (cb_mode == 1) {
        const unsigned short* cw = (const unsigned short*)cbraw;
        f16x8 h;
        for (int j = 0; j < 8; ++j) h[j] = (f16)bf16_to_f32(cw[t * 8 + j]);
        *(f16x8*)&cbL[t * 8] = h;
    } else {
        ((uint4*)cbL)[t] = ((const uint4*)cbraw)[t];  // raw f16 copy, 16 B/thread
    }
    __syncthreads();

    // ---------------- GEMM ------------------------------------------------------
    const int m0 = blockIdx.y * 128;
    const int n0 = blockIdx.x * 128;
    const int w = t >> 6, l = t & 63, quad = l >> 4, lr = l & 15;
    const int wm = (w >> 1) * 64, wn = (w & 1) * 64;

    f32x4 acc[4][4] = {};

    for (int kb = 0; kb < KDIM / 64; ++kb) {
        const int k0 = kb * 64;
        // -- A staging: LDS slot (row, j) holds global k-chunk gc = j ^ (row&7)
#pragma unroll
        for (int cc = 0; cc < 4; ++cc) {
            int c = cc * 256 + t, row = c >> 3, j = c & 7;
            int gc = j ^ (row & 7);
            f16x8 h;
            if (!x_bf16) {
                const float4* p = (const float4*)((const float*)xraw +
                                  (size_t)(m0 + row) * KDIM + k0 + gc * 8);
                float4 a = p[0], b = p[1];
                h[0] = (f16)a.x; h[1] = (f16)a.y; h[2] = (f16)a.z; h[3] = (f16)a.w;
                h[4] = (f16)b.x; h[5] = (f16)b.y; h[6] = (f16)b.z; h[7] = (f16)b.w;
            } else {
                const unsigned short* p = (const unsigned short*)xraw +
                                          (size_t)(m0 + row) * KDIM + k0 + gc * 8;
                ushort4 a = *(const ushort4*)p, b = *(const ushort4*)(p + 4);
                h[0] = (f16)bf16_to_f32(a.x); h[1] = (f16)bf16_to_f32(a.y);
                h[2] = (f16)bf16_to_f32(a.z); h[3] = (f16)bf16_to_f32(a.w);
                h[4] = (f16)bf16_to_f32(b.x); h[5] = (f16)bf16_to_f32(b.y);
                h[6] = (f16)bf16_to_f32(b.z); h[7] = (f16)bf16_to_f32(b.w);
            }
            *(f16x8*)&As[row * 64 + j * 8] = h;
        }
        // -- B staging: gather codes, copy decoded rows cbL -> Bs
#pragma unroll
        for (int cc = 0; cc < 4; ++cc) {
            int c = cc * 256 + t, row = c >> 3, j = c & 7;
            int gc = j ^ (row & 7);
            int cpos = (n0 + row) * (KDIM / 8) + kb * 8 + gc;
            int code = idx64 ? (int)((const long long*)idxraw)[cpos]
                             : ((const int*)idxraw)[cpos];
            *(f16x8*)&Bs[row * 64 + j * 8] = *(const f16x8*)&cbL[code * 8];
        }
        __syncthreads();

        // -- MFMA: A[m=lane&15][k=quad*8+j], B[n=lane&15][k=quad*8+j]
#pragma unroll
        for (int ks = 0; ks < 2; ++ks) {
            f16x8 af[4], bf[4];
            int gc = ks * 4 + quad;
            int cc2 = gc ^ (lr & 7);
#pragma unroll
            for (int mt = 0; mt < 4; ++mt)
                af[mt] = *(const f16x8*)&As[(wm + mt * 16 + lr) * 64 + cc2 * 8];
#pragma unroll
            for (int nt = 0; nt < 4; ++nt)
                bf[nt] = *(const f16x8*)&Bs[(wn + nt * 16 + lr) * 64 + cc2 * 8];
#pragma unroll
            for (int mt = 0; mt < 4; ++mt)
#pragma unroll
                for (int nt = 0; nt < 4; ++nt)
                    acc[mt][nt] = __builtin_amdgcn_mfma_f32_16x16x32_f16(
                        af[mt], bf[nt], acc[mt][nt], 0, 0, 0);
        }
        __syncthreads();
    }

    // ---------------- epilogue: C/D col(N)=lane&15, row(M)=quad*4+reg ----------
    if (x_bf16) {
        unsigned short* Cb = (unsigned short*)outraw;
#pragma unroll
        for (int mt = 0; mt < 4; ++mt)
#pragma unroll
            for (int nt = 0; nt < 4; ++nt) {
                int colg = n0 + wn + nt * 16 + lr;
#pragma unroll
                for (int r = 0; r < 4; ++r) {
                    int rowg = m0 + wm + mt * 16 + quad * 4 + r;
                    Cb[(size_t)rowg * NDIM + colg] = f32_to_bf16(acc[mt][nt][r]);
                }
            }
    } else {
        float* Cf = (float*)outraw;
#pragma unroll
        for (int mt = 0; mt < 4; ++mt)
#pragma unroll
            for (int nt = 0; nt < 4; ++nt) {
                int colg = n0 + wn + nt * 16 + lr;
#pragma unroll
                for (int r = 0; r < 4; ++r) {
                    int rowg = m0 + wm + mt * 16 + quad * 4 + r;
                    Cf[(size_t)rowg * NDIM + colg] = acc[mt][nt][r];
                }
            }
    }
}

extern "C" void kernel_launch(void* const* d_in, const int* in_sizes, int n_in,
                              void* d_out, int out_size, void* d_ws, size_t ws_size,
                              hipStream_t stream) {
    (void)in_sizes; (void)n_in; (void)out_size; (void)d_ws; (void)ws_size;
    dim3 grid(NDIM / 128, MDIM / 128);
    crom_fused<<<grid, 256, 0, stream>>>(d_in[0], d_in[1], d_in[2], d_out);
}

// Round 4
// 554.403 us; speedup vs baseline: 1.9038x; 1.9038x over previous
//
#include <hip/hip_runtime.h>

// out[m,n] = sum_k f16(x[m,k]) * W[n,k],  W = codebook[indices].reshape(4096,4096)
// M=8192, N=4096, K=4096, codebook 256x8. x/out are bf16 on the wire (verified
// round 3); cb/idx dtypes sniffed on-device.
//
// FAST PATH (ws_size >= 96MiB+4KiB): detect -> dequant W (f16, ws+0) ->
//   cvt x (f16, ws+32MiB) -> m97-style GEMM (128x128, BK=64,
//   global_load_lds x16B, XOR swizzle folded into global src addr).
// FALLBACK (small ws): round-3 fused kernel, zero workspace (proven, 920us).

typedef _Float16 f16;
typedef _Float16 f16x8 __attribute__((ext_vector_type(8)));
typedef float f32x4 __attribute__((ext_vector_type(4)));

#define KDIM 4096
#define NDIM 4096
#define MDIM 8192

struct Flags { int cb_mode; int x_bf16; int idx64; int pad; };

__device__ inline float bf16_to_f32(unsigned short w) {
    union { unsigned u; float f; } c; c.u = ((unsigned)w) << 16; return c.f;
}
__device__ inline unsigned short f32_to_bf16(float f) {
    union { float f; unsigned u; } c; c.f = f;
    unsigned r = c.u + 0x7FFFu + ((c.u >> 16) & 1u);   // RNE
    return (unsigned short)(r >> 16);
}

// ============================ FAST PATH ======================================

__global__ __launch_bounds__(256) void crom_detect(const unsigned short* __restrict__ cbw,
                                                   const unsigned short* __restrict__ xw,
                                                   const unsigned* __restrict__ idxw,
                                                   Flags* __restrict__ flags) {
    __shared__ int cnt[4];
    const int t = threadIdx.x;
    if (t < 4) cnt[t] = 0;
    __syncthreads();
    int c_cb = 0, c_f32ok = 1, c_x = 0, c_z = 0;
    for (int j = 0; j < 8; ++j) {
        int e5 = (cbw[t * 8 + j] >> 10) & 31;         // f16 exp: f16 ~32%, bf16-bits ~99%
        c_cb += (e5 == 15) || (e5 == 16);
    }
    const float* cbf = (const float*)cbw;             // f32 test: exact f16 round-trip
    for (int j = 0; j < 4; ++j) {
        float v = cbf[t * 4 + j];
        if (!(__builtin_fabsf(v) < 1024.0f)) c_f32ok = 0;
        else { f16 h = (f16)v; if ((float)h != v) c_f32ok = 0; }
    }
    for (int j = 0; j < 8; ++j) {
        int e8 = (xw[t * 8 + j] >> 7) & 255;          // bf16 exp: bf16 ~100%, f32-halves ~53%
        c_x += (e8 >= 115) && (e8 <= 131);
    }
    for (int j = 1; j < 8; j += 2) c_z += (idxw[t * 8 + j] == 0);  // i64 high words
    atomicAdd(&cnt[0], c_cb);
    atomicAdd(&cnt[1], c_f32ok);
    atomicAdd(&cnt[2], c_x);
    atomicAdd(&cnt[3], c_z);
    __syncthreads();
    if (t == 0) {
        flags->cb_mode = (cnt[1] == 256) ? 2 : ((cnt[0] > 1300) ? 1 : 0); // 0=f16,1=bf16,2=f32
        flags->x_bf16  = cnt[2] > 1600;
        flags->idx64   = cnt[3] > 512;
    }
}

// gather codes -> dense W[N][K] f16 (one 16B code per thread)
__global__ __launch_bounds__(256) void crom_dequant(const void* __restrict__ idxraw,
                                                    const void* __restrict__ cbraw,
                                                    uint4* __restrict__ W,
                                                    const Flags* __restrict__ flags) {
    __shared__ __align__(16) f16 cbL[256 * 8];
    const int t = threadIdx.x;
    const int cb_mode = flags->cb_mode;
    if (cb_mode == 2) {
        const float* cf = (const float*)cbraw;
        f16x8 h;
        for (int j = 0; j < 8; ++j) h[j] = (f16)cf[t * 8 + j];
        *(f16x8*)&cbL[t * 8] = h;
    } else if (cb_mode == 1) {
        const unsigned short* cw = (const unsigned short*)cbraw;
        f16x8 h;
        for (int j = 0; j < 8; ++j) h[j] = (f16)bf16_to_f32(cw[t * 8 + j]);
        *(f16x8*)&cbL[t * 8] = h;
    } else {
        ((uint4*)cbL)[t] = ((const uint4*)cbraw)[t];
    }
    __syncthreads();
    int i = blockIdx.x * 256 + t;                     // 2,097,152 codes
    int code = flags->idx64 ? (int)((const long long*)idxraw)[i]
                            : ((const int*)idxraw)[i];
    W[i] = *(const uint4*)&cbL[code * 8];
}

// x -> f16, 8 elements/thread
__global__ __launch_bounds__(256) void crom_cvt_x(const void* __restrict__ X,
                                                  f16x8* __restrict__ Xh,
                                                  const Flags* __restrict__ flags) {
    int i = blockIdx.x * 256 + threadIdx.x;           // 4,194,304 groups of 8
    f16x8 h;
    if (flags->x_bf16) {
        ushort4 a = ((const ushort4*)X)[2 * i];
        ushort4 b = ((const ushort4*)X)[2 * i + 1];
        h[0] = (f16)bf16_to_f32(a.x); h[1] = (f16)bf16_to_f32(a.y);
        h[2] = (f16)bf16_to_f32(a.z); h[3] = (f16)bf16_to_f32(a.w);
        h[4] = (f16)bf16_to_f32(b.x); h[5] = (f16)bf16_to_f32(b.y);
        h[6] = (f16)bf16_to_f32(b.z); h[7] = (f16)bf16_to_f32(b.w);
    } else {
        float4 a = ((const float4*)X)[2 * i];
        float4 b = ((const float4*)X)[2 * i + 1];
        h[0] = (f16)a.x; h[1] = (f16)a.y; h[2] = (f16)a.z; h[3] = (f16)a.w;
        h[4] = (f16)b.x; h[5] = (f16)b.y; h[6] = (f16)b.z; h[7] = (f16)b.w;
    }
    Xh[i] = h;
}

// C[M,N] = A[M,K]*B[N,K]^T. 4 waves; wave = 64x64 quadrant = 4x4 16x16 tiles.
// LDS slot (row, j) holds global k-chunk j ^ (row&7) (swizzle in global src).
__global__ __launch_bounds__(256) void crom_gemm(const f16* __restrict__ A,
                                                 const f16* __restrict__ B,
                                                 void* __restrict__ Cout,
                                                 const Flags* __restrict__ flags) {
    __shared__ __align__(16) f16 As[128 * 64];
    __shared__ __align__(16) f16 Bs[128 * 64];

    const int tid  = threadIdx.x;
    const int w    = tid >> 6;
    const int l    = tid & 63;
    const int m0   = blockIdx.y * 128;
    const int n0   = blockIdx.x * 128;
    const int wm   = (w >> 1) * 64;
    const int wn   = (w & 1) * 64;
    const int quad = l >> 4;
    const int lr   = l & 15;
    const int out_bf16 = flags->x_bf16;

    f32x4 acc[4][4] = {};

    for (int kb = 0; kb < KDIM / 64; ++kb) {
        const int k0 = kb * 64;
#pragma unroll
        for (int it = 0; it < 4; ++it) {
            int c   = it * 256 + w * 64 + l;          // linear LDS chunk [0,1024)
            int row = c >> 3;
            int sc  = (c & 7) ^ (row & 7);            // swizzle folded into src addr
            const f16* ga = A + (size_t)(m0 + row) * KDIM + k0 + sc * 8;
            const f16* gb = B + (size_t)(n0 + row) * KDIM + k0 + sc * 8;
            f16* la = &As[(size_t)(it * 256 + w * 64) * 8];   // wave-uniform base
            f16* lb = &Bs[(size_t)(it * 256 + w * 64) * 8];
            __builtin_amdgcn_global_load_lds(
                (const __attribute__((address_space(1))) void*)ga,
                (__attribute__((address_space(3))) void*)la, 16, 0, 0);
            __builtin_amdgcn_global_load_lds(
                (const __attribute__((address_space(1))) void*)gb,
                (__attribute__((address_space(3))) void*)lb, 16, 0, 0);
        }
        __syncthreads();

#pragma unroll
        for (int ks = 0; ks < 2; ++ks) {
            f16x8 af[4], bf[4];
            const int gc = ks * 4 + quad;
            const int cc = gc ^ (lr & 7);             // row&7 == lr&7 for all tiles
#pragma unroll
            for (int mt = 0; mt < 4; ++mt)
                af[mt] = *(const f16x8*)&As[(wm + mt * 16 + lr) * 64 + cc * 8];
#pragma unroll
            for (int nt = 0; nt < 4; ++nt)
                bf[nt] = *(const f16x8*)&Bs[(wn + nt * 16 + lr) * 64 + cc * 8];
#pragma unroll
            for (int mt = 0; mt < 4; ++mt)
#pragma unroll
                for (int nt = 0; nt < 4; ++nt)
                    acc[mt][nt] = __builtin_amdgcn_mfma_f32_16x16x32_f16(
                        af[mt], bf[nt], acc[mt][nt], 0, 0, 0);
        }
        __syncthreads();
    }

    // epilogue: C/D col(N)=lane&15, row(M)=quad*4+reg
    if (out_bf16) {
        unsigned short* Cb = (unsigned short*)Cout;
#pragma unroll
        for (int mt = 0; mt < 4; ++mt)
#pragma unroll
            for (int nt = 0; nt < 4; ++nt) {
                int colg = n0 + wn + nt * 16 + lr;
#pragma unroll
                for (int r = 0; r < 4; ++r) {
                    int rowg = m0 + wm + mt * 16 + quad * 4 + r;
                    Cb[(size_t)rowg * NDIM + colg] = f32_to_bf16(acc[mt][nt][r]);
                }
            }
    } else {
        float* Cf = (float*)Cout;
#pragma unroll
        for (int mt = 0; mt < 4; ++mt)
#pragma unroll
            for (int nt = 0; nt < 4; ++nt) {
                int colg = n0 + wn + nt * 16 + lr;
#pragma unroll
                for (int r = 0; r < 4; ++r) {
                    int rowg = m0 + wm + mt * 16 + quad * 4 + r;
                    Cf[(size_t)rowg * NDIM + colg] = acc[mt][nt][r];
                }
            }
    }
}

// ============================ FALLBACK (round-3 fused, proven) ===============

__global__ __launch_bounds__(256) void crom_fused(const void* __restrict__ xraw,
                                                  const void* __restrict__ cbraw,
                                                  const void* __restrict__ idxraw,
                                                  void* __restrict__ outraw) {
    __shared__ __align__(16) f16 cbL[256 * 8];
    __shared__ __align__(16) f16 As[128 * 64];
    __shared__ __align__(16) f16 Bs[128 * 64];
    __shared__ int flagsL[4];

    const int t = threadIdx.x;
    {
        int c_cb = 0, c_f32ok = 1, c_x = 0, c_z = 0;
        const unsigned short* cbw = (const unsigned short*)cbraw;
        for (int j = 0; j < 8; ++j) {
            int e5 = (cbw[t * 8 + j] >> 10) & 31;
            c_cb += (e5 == 15) || (e5 == 16);
        }
        const float* cbf = (const float*)cbraw;
        for (int j = 0; j < 4; ++j) {
            float v = cbf[t * 4 + j];
            if (!(__builtin_fabsf(v) < 1024.0f)) c_f32ok = 0;
            else { f16 h = (f16)v; if ((float)h != v) c_f32ok = 0; }
        }
        const unsigned short* xw = (const unsigned short*)xraw;
        for (int j = 0; j < 8; ++j) {
            int e8 = (xw[t * 8 + j] >> 7) & 255;
            c_x += (e8 >= 115) && (e8 <= 131);
        }
        const unsigned* iw = (const unsigned*)idxraw;
        for (int j = 1; j < 8; j += 2) c_z += (iw[t * 8 + j] == 0);
        if (t < 4) flagsL[t] = 0;
        __syncthreads();
        atomicAdd(&flagsL[0], c_cb);
        atomicAdd(&flagsL[1], c_f32ok);
        atomicAdd(&flagsL[2], c_x);
        atomicAdd(&flagsL[3], c_z);
        __syncthreads();
    }
    const int cb_mode = (flagsL[1] == 256) ? 2 : ((flagsL[0] > 1300) ? 1 : 0);
    const int x_bf16  = flagsL[2] > 1600;
    const int idx64   = flagsL[3] > 512;

    if (cb_mode == 2) {
        const float* cf = (const float*)cbraw;
        f16x8 h;
        for (int j = 0; j < 8; ++j) h[j] = (f16)cf[t * 8 + j];
        *(f16x8*)&cbL[t * 8] = h;
    } else if (cb_mode == 1) {
        const unsigned short* cw = (const unsigned short*)cbraw;
        f16x8 h;
        for (int j = 0; j < 8; ++j) h[j] = (f16)bf16_to_f32(cw[t * 8 + j]);
        *(f16x8*)&cbL[t * 8] = h;
    } else {
        ((uint4*)cbL)[t] = ((const uint4*)cbraw)[t];
    }
    __syncthreads();

    const int m0 = blockIdx.y * 128;
    const int n0 = blockIdx.x * 128;
    const int w = t >> 6, l = t & 63, quad = l >> 4, lr = l & 15;
    const int wm = (w >> 1) * 64, wn = (w & 1) * 64;

    f32x4 acc[4][4] = {};

    for (int kb = 0; kb < KDIM / 64; ++kb) {
        const int k0 = kb * 64;
#pragma unroll
        for (int cc = 0; cc < 4; ++cc) {
            int c = cc * 256 + t, row = c >> 3, j = c & 7;
            int gc = j ^ (row & 7);
            f16x8 h;
            if (!x_bf16) {
                const float4* p = (const float4*)((const float*)xraw +
                                  (size_t)(m0 + row) * KDIM + k0 + gc * 8);
                float4 a = p[0], b = p[1];
                h[0] = (f16)a.x; h[1] = (f16)a.y; h[2] = (f16)a.z; h[3] = (f16)a.w;
                h[4] = (f16)b.x; h[5] = (f16)b.y; h[6] = (f16)b.z; h[7] = (f16)b.w;
            } else {
                const unsigned short* p = (const unsigned short*)xraw +
                                          (size_t)(m0 + row) * KDIM + k0 + gc * 8;
                ushort4 a = *(const ushort4*)p, b = *(const ushort4*)(p + 4);
                h[0] = (f16)bf16_to_f32(a.x); h[1] = (f16)bf16_to_f32(a.y);
                h[2] = (f16)bf16_to_f32(a.z); h[3] = (f16)bf16_to_f32(a.w);
                h[4] = (f16)bf16_to_f32(b.x); h[5] = (f16)bf16_to_f32(b.y);
                h[6] = (f16)bf16_to_f32(b.z); h[7] = (f16)bf16_to_f32(b.w);
            }
            *(f16x8*)&As[row * 64 + j * 8] = h;
        }
#pragma unroll
        for (int cc = 0; cc < 4; ++cc) {
            int c = cc * 256 + t, row = c >> 3, j = c & 7;
            int gc = j ^ (row & 7);
            int cpos = (n0 + row) * (KDIM / 8) + kb * 8 + gc;
            int code = idx64 ? (int)((const long long*)idxraw)[cpos]
                             : ((const int*)idxraw)[cpos];
            *(f16x8*)&Bs[row * 64 + j * 8] = *(const f16x8*)&cbL[code * 8];
        }
        __syncthreads();

#pragma unroll
        for (int ks = 0; ks < 2; ++ks) {
            f16x8 af[4], bf[4];
            int gc = ks * 4 + quad;
            int cc2 = gc ^ (lr & 7);
#pragma unroll
            for (int mt = 0; mt < 4; ++mt)
                af[mt] = *(const f16x8*)&As[(wm + mt * 16 + lr) * 64 + cc2 * 8];
#pragma unroll
            for (int nt = 0; nt < 4; ++nt)
                bf[nt] = *(const f16x8*)&Bs[(wn + nt * 16 + lr) * 64 + cc2 * 8];
#pragma unroll
            for (int mt = 0; mt < 4; ++mt)
#pragma unroll
                for (int nt = 0; nt < 4; ++nt)
                    acc[mt][nt] = __builtin_amdgcn_mfma_f32_16x16x32_f16(
                        af[mt], bf[nt], acc[mt][nt], 0, 0, 0);
        }
        __syncthreads();
    }

    if (x_bf16) {
        unsigned short* Cb = (unsigned short*)outraw;
#pragma unroll
        for (int mt = 0; mt < 4; ++mt)
#pragma unroll
            for (int nt = 0; nt < 4; ++nt) {
                int colg = n0 + wn + nt * 16 + lr;
#pragma unroll
                for (int r = 0; r < 4; ++r) {
                    int rowg = m0 + wm + mt * 16 + quad * 4 + r;
                    Cb[(size_t)rowg * NDIM + colg] = f32_to_bf16(acc[mt][nt][r]);
                }
            }
    } else {
        float* Cf = (float*)outraw;
#pragma unroll
        for (int mt = 0; mt < 4; ++mt)
#pragma unroll
            for (int nt = 0; nt < 4; ++nt) {
                int colg = n0 + wn + nt * 16 + lr;
#pragma unroll
                for (int r = 0; r < 4; ++r) {
                    int rowg = m0 + wm + mt * 16 + quad * 4 + r;
                    Cf[(size_t)rowg * NDIM + colg] = acc[mt][nt][r];
                }
            }
    }
}

// ============================ launcher =======================================

extern "C" void kernel_launch(void* const* d_in, const int* in_sizes, int n_in,
                              void* d_out, int out_size, void* d_ws, size_t ws_size,
                              hipStream_t stream) {
    (void)in_sizes; (void)n_in; (void)out_size;
    const void* x   = d_in[0];
    const void* cb  = d_in[1];
    const void* idx = d_in[2];

    const size_t NEED = (size_t)96 * 1024 * 1024 + 4096;
    dim3 grid(NDIM / 128, MDIM / 128);

    if (ws_size >= NEED) {
        f16*   Wq    = (f16*)d_ws;                                        // 32 MiB
        f16*   Xh    = (f16*)((char*)d_ws + (size_t)32 * 1024 * 1024);    // 64 MiB
        Flags* flags = (Flags*)((char*)d_ws + (size_t)96 * 1024 * 1024);  // 16 B

        crom_detect<<<1, 256, 0, stream>>>((const unsigned short*)cb,
                                           (const unsigned short*)x,
                                           (const unsigned*)idx, flags);
        crom_dequant<<<2097152 / 256, 256, 0, stream>>>(idx, cb, (uint4*)Wq, flags);
        crom_cvt_x<<<(33554432 / 8) / 256, 256, 0, stream>>>(x, (f16x8*)Xh, flags);
        crom_gemm<<<grid, 256, 0, stream>>>(Xh, Wq, d_out, flags);
    } else {
        crom_fused<<<grid, 256, 0, stream>>>(x, cb, idx, d_out);
    }
}